// Round 5
// baseline (197.498 us; speedup 1.0000x reference)
//
#include <hip/hip_runtime.h>

// B=16, T=1024, N=1024, D=256, WIN=64
// outputs (flat): R (B,T,2D) = [A@V, Q]   : 8388608 f32
//                 alignments (B,N,T) = A^T: 16777216 f32
//                 max_att (B,T)           : 16384 f32
//
// v5: two kernels.
//  - zero_aligns: streams 67 MB of zeros at store BW, full occupancy.
//  - attn_v5: 1024 blocks x 512 thr (2 queries/wave -> 8192 waves = 32/CU
//    potential; LDS 38.1 KB -> 4 blocks/CU). K staged in d-halves into LDS
//    (kills the K scatter), V staged through the SAME buffer after QK
//    (kills the 512 MB L2 V re-read of v4). Window-row alignment strip
//    (4 MB, one 64B line per row) overwrites the zeros.

#define BB 16
#define TT 1024
#define NN 1024
#define DD 256
#define WIN 64
#define TBLK 16          // queries per block
#define NT 512           // threads (8 waves, 2 queries each)

#define R_ELEMS   (16u*1024u*512u)        // 8388608
#define ALN_ELEMS (16u*1024u*1024u)       // 16777216

#define LSTR 132         // LDS row stride (dwords) for 128-d half tiles; 132%32==4

__global__ __launch_bounds__(256) void zero_aligns(float4* __restrict__ p) {
    const float4 z = make_float4(0.f, 0.f, 0.f, 0.f);
    size_t base = (size_t)blockIdx.x * 1024 + threadIdx.x;
    #pragma unroll
    for (int k = 0; k < 4; ++k) p[base + k * 256] = z;
}

__global__ __launch_bounds__(NT, 8) void attn_v5(
    const float* __restrict__ Q, const float* __restrict__ K,
    const float* __restrict__ V, const int* __restrict__ prev_in,
    float* __restrict__ out)
{
    __shared__ float ks[WIN * LSTR];        // 33792 B: K-half / V-half tile
    __shared__ float p_lds[TBLK][WIN + 4];  // 4352 B : probabilities [t][j]

    float* Rout   = out;
    float* aligns = out + R_ELEMS;
    float* maxatt = out + R_ELEMS + ALN_ELEMS;

    const int tid  = threadIdx.x;
    const int lane = tid & 63;
    const int w    = tid >> 6;              // wave 0..7; queries 2w, 2w+1
    const int b    = blockIdx.x >> 6;       // 64 blocks per batch
    const int t0   = (blockIdx.x & 63) * TBLK;
    const int prev = prev_in[b];

    const float* qb = Q + ((size_t)b * TT + t0 + 2 * w) * DD;

    // ================= QK^T over two 128-d halves =================
    float acc0 = 0.f, acc1 = 0.f;
    #pragma unroll
    for (int h = 0; h < 2; ++h) {
        if (h) __syncthreads();             // previous half's readers done
        // stage K[prev..prev+64)[h*128..h*128+128): 2048 float4, coalesced
        const float4* Ksrc = (const float4*)(K + ((size_t)b * NN + prev) * DD + h * 128);
        #pragma unroll
        for (int k = 0; k < 4; ++k) {
            int t4 = tid + k * NT;          // 0..2047
            int r = t4 >> 5, c = t4 & 31;
            float4 v = Ksrc[(size_t)r * 64 + c];
            *(float4*)&ks[r * LSTR + c * 4] = v;
        }
        __syncthreads();

        const float* qh = qb + h * 128;
        #pragma unroll 8
        for (int d4 = 0; d4 < 32; ++d4) {
            float4 kk = *(const float4*)&ks[lane * LSTR + d4 * 4];  // conflict-free
            float4 q0 = ((const float4*)qh)[d4];                    // wave-uniform
            float4 q1 = ((const float4*)(qh + DD))[d4];
            acc0 = fmaf(q0.x, kk.x, fmaf(q0.y, kk.y, fmaf(q0.z, kk.z, fmaf(q0.w, kk.w, acc0))));
            acc1 = fmaf(q1.x, kk.x, fmaf(q1.y, kk.y, fmaf(q1.z, kk.z, fmaf(q1.w, kk.w, acc1))));
        }
    }

    // ================= softmax + argmax (wave-local) =================
    #pragma unroll
    for (int t = 0; t < 2; ++t) {
        float v = (t ? acc1 : acc0) * 0.0625f;   // 1/sqrt(256)

        float m = v;
        #pragma unroll
        for (int off = 32; off; off >>= 1) m = fmaxf(m, __shfl_xor(m, off));

        float e = expf(v - m);
        float s = e;
        #pragma unroll
        for (int off = 32; off; off >>= 1) s += __shfl_xor(s, off);

        p_lds[2 * w + t][lane] = e / s;

        float av = v; int ai = lane;
        #pragma unroll
        for (int off = 32; off; off >>= 1) {
            float ov = __shfl_xor(av, off);
            int   oi = __shfl_xor(ai, off);
            if (ov > av || (ov == av && oi < ai)) { av = ov; ai = oi; }
        }
        if (lane == 0) maxatt[(size_t)b * TT + t0 + 2 * w + t] = (float)(prev + ai);
    }

    // ================= PV over two 128-d halves (V through LDS) =========
    // lane = 32*jpar + dc: jpar in {0,1} handles even/odd j, dc = d-chunk.
    const int jpar = lane >> 5, dc = lane & 31;
    float* Rrow = Rout + ((size_t)b * TT + t0 + 2 * w + jpar) * (2 * DD);
    const int tq0 = 2 * w, tq1 = 2 * w + 1;

    #pragma unroll
    for (int h = 0; h < 2; ++h) {
        __syncthreads();                    // QK/PV readers of ks done
        const float4* Vsrc = (const float4*)(V + ((size_t)b * NN + prev) * DD + h * 128);
        #pragma unroll
        for (int k = 0; k < 4; ++k) {
            int t4 = tid + k * NT;
            int r = t4 >> 5, c = t4 & 31;
            float4 v = Vsrc[(size_t)r * 64 + c];
            *(float4*)&ks[r * LSTR + c * 4] = v;
        }
        __syncthreads();

        float4 o0 = make_float4(0.f, 0.f, 0.f, 0.f);
        float4 o1 = make_float4(0.f, 0.f, 0.f, 0.f);
        #pragma unroll 8
        for (int j2 = 0; j2 < 32; ++j2) {
            int j = j2 * 2 + jpar;
            float4 vv = *(const float4*)&ks[j * LSTR + dc * 4];
            float pa = p_lds[tq0][j];       // 2 addrs/wave: broadcast-cheap
            float pb = p_lds[tq1][j];
            o0.x = fmaf(pa, vv.x, o0.x); o0.y = fmaf(pa, vv.y, o0.y);
            o0.z = fmaf(pa, vv.z, o0.z); o0.w = fmaf(pa, vv.w, o0.w);
            o1.x = fmaf(pb, vv.x, o1.x); o1.y = fmaf(pb, vv.y, o1.y);
            o1.z = fmaf(pb, vv.z, o1.z); o1.w = fmaf(pb, vv.w, o1.w);
        }
        // combine even/odd-j partials across the jpar split
        o0.x += __shfl_xor(o0.x, 32); o0.y += __shfl_xor(o0.y, 32);
        o0.z += __shfl_xor(o0.z, 32); o0.w += __shfl_xor(o0.w, 32);
        o1.x += __shfl_xor(o1.x, 32); o1.y += __shfl_xor(o1.y, 32);
        o1.z += __shfl_xor(o1.z, 32); o1.w += __shfl_xor(o1.w, 32);
        // jpar 0 stores query 2w, jpar 1 stores query 2w+1 (both have sums)
        float4 ov = jpar ? o1 : o0;
        ((float4*)Rrow)[h * 32 + dc] = ov;
    }

    // Q copy into R[:, D:2D): 2 rows x 1KB per wave, coalesced (Q is L1-hot)
    {
        const float4* Qr = (const float4*)(qb + jpar * DD);
        ((float4*)(Rrow + DD))[dc]      = Qr[dc];
        ((float4*)(Rrow + DD))[32 + dc] = Qr[32 + dc];
    }

    // ---- window-row alignment strip: 64 rows x 16 floats (one 64B line) ----
    // p_lds stable since softmax barrier (first PV __syncthreads covers it).
    if (tid < 256) {
        int j = tid >> 2, cg = tid & 3;
        float4 v;
        v.x = p_lds[cg * 4 + 0][j];
        v.y = p_lds[cg * 4 + 1][j];
        v.z = p_lds[cg * 4 + 2][j];
        v.w = p_lds[cg * 4 + 3][j];
        *(float4*)(aligns + ((size_t)b * NN + prev + j) * TT + t0 + cg * 4) = v;
    }
}

extern "C" void kernel_launch(void* const* d_in, const int* in_sizes, int n_in,
                              void* d_out, int out_size, void* d_ws, size_t ws_size,
                              hipStream_t stream) {
    const float* Q = (const float*)d_in[0];
    const float* K = (const float*)d_in[1];
    const float* V = (const float*)d_in[2];
    const int* prev = (const int*)d_in[3];
    float* out = (float*)d_out;

    // 1) zero the full alignments region at streaming-store bandwidth
    zero_aligns<<<ALN_ELEMS / (4 * 1024), 256, 0, stream>>>((float4*)(out + R_ELEMS));
    // 2) attention; overwrites the 64 window rows per batch
    attn_v5<<<BB * TT / TBLK, NT, 0, stream>>>(Q, K, V, prev, out);
}

// Round 6
// 190.234 us; speedup vs baseline: 1.0382x; 1.0382x over previous
//
#include <hip/hip_runtime.h>

// B=16, T=1024, N=1024, D=256, WIN=64
// outputs (flat): R (B,T,2D) = [A@V, Q]   : 8388608 f32
//                 alignments (B,N,T) = A^T: 16777216 f32
//                 max_att (B,T)           : 16384 f32
//
// v6: single kernel, 512 blocks x 1024 threads (16 waves, 2 queries/wave)
//  -> 8192 waves; LDS 42.5 KB -> 2 blocks/CU -> 32 waves/CU (100% cap).
//  K window staged in 128-d halves into padded LDS (conflict-free b128
//  reads, stride 132%32==4). V read directly from global (L2-hot window,
//  no extra barriers). Each block writes its FULL alignment column strip
//  (1024 rows x 32 floats = 128B full lines): zeros outside the window,
//  probabilities inside — no separate zero kernel, no partial lines.

#define BB 16
#define TT 1024
#define NN 1024
#define DD 256
#define WIN 64
#define TBLK 32          // queries per block
#define NT 1024          // 16 waves, 2 queries each

#define R_ELEMS   (16u*1024u*512u)        // 8388608
#define ALN_ELEMS (16u*1024u*1024u)       // 16777216

#define LSTR 132         // LDS row stride (dwords); 132%32==4 -> conflict-free

__global__ __launch_bounds__(NT, 8) void attn_v6(
    const float* __restrict__ Q, const float* __restrict__ K,
    const float* __restrict__ V, const int* __restrict__ prev_in,
    float* __restrict__ out)
{
    __shared__ float ks[WIN * LSTR];        // 33792 B: K half-tile
    __shared__ float p_lds[TBLK][WIN + 4];  // 8704 B : probabilities [t][j]

    float* Rout   = out;
    float* aligns = out + R_ELEMS;
    float* maxatt = out + R_ELEMS + ALN_ELEMS;

    const int tid  = threadIdx.x;
    const int lane = tid & 63;
    const int w    = tid >> 6;              // wave 0..15; queries 2w, 2w+1
    const int b    = blockIdx.x >> 5;       // 32 blocks per batch
    const int t0   = (blockIdx.x & 31) * TBLK;
    const int prev = prev_in[b];

    const float* qb = Q + ((size_t)b * TT + t0 + 2 * w) * DD;

    // ================= QK^T over two 128-d halves =================
    float acc0 = 0.f, acc1 = 0.f;
    #pragma unroll
    for (int h = 0; h < 2; ++h) {
        if (h) __syncthreads();             // previous half's readers done
        // stage K[prev..prev+64)[h*128..): 2048 float4, 2 per thread
        const float4* Ksrc = (const float4*)(K + ((size_t)b * NN + prev) * DD + h * 128);
        #pragma unroll
        for (int k = 0; k < 2; ++k) {
            int t4 = tid + k * NT;          // 0..2047
            int r = t4 >> 5, c = t4 & 31;
            float4 v = Ksrc[(size_t)r * 64 + c];
            *(float4*)&ks[r * LSTR + c * 4] = v;
        }
        __syncthreads();

        const float* qh = qb + h * 128;
        #pragma unroll 8
        for (int d4 = 0; d4 < 32; ++d4) {
            float4 kk = *(const float4*)&ks[lane * LSTR + d4 * 4];  // conflict-free
            float4 q0 = ((const float4*)qh)[d4];                    // wave-uniform
            float4 q1 = ((const float4*)(qh + DD))[d4];
            acc0 = fmaf(q0.x, kk.x, fmaf(q0.y, kk.y, fmaf(q0.z, kk.z, fmaf(q0.w, kk.w, acc0))));
            acc1 = fmaf(q1.x, kk.x, fmaf(q1.y, kk.y, fmaf(q1.z, kk.z, fmaf(q1.w, kk.w, acc1))));
        }
    }

    // ================= softmax + argmax (wave-local) =================
    const int tq0 = 2 * w, tq1 = 2 * w + 1;
    #pragma unroll
    for (int t = 0; t < 2; ++t) {
        float v = (t ? acc1 : acc0) * 0.0625f;   // 1/sqrt(256)

        float m = v;
        #pragma unroll
        for (int off = 32; off; off >>= 1) m = fmaxf(m, __shfl_xor(m, off));

        float e = expf(v - m);
        float s = e;
        #pragma unroll
        for (int off = 32; off; off >>= 1) s += __shfl_xor(s, off);

        p_lds[2 * w + t][lane] = e / s;

        float av = v; int ai = lane;
        #pragma unroll
        for (int off = 32; off; off >>= 1) {
            float ov = __shfl_xor(av, off);
            int   oi = __shfl_xor(ai, off);
            if (ov > av || (ov == av && oi < ai)) { av = ov; ai = oi; }
        }
        if (lane == 0) maxatt[(size_t)b * TT + t0 + 2 * w + t] = (float)(prev + ai);
    }

    // ================= PV direct from global (L2-hot V window) ===========
    // lane = d-chunk (64 x float4 = full 256-d row); own wave's p rows only
    // (written by this wave above -> no barrier needed, just lgkmcnt).
    {
        const float4* V4 = (const float4*)(V + ((size_t)b * NN + prev) * DD);
        float4 o0 = make_float4(0.f, 0.f, 0.f, 0.f);
        float4 o1 = make_float4(0.f, 0.f, 0.f, 0.f);
        #pragma unroll 8
        for (int j = 0; j < WIN; ++j) {
            float4 vv = V4[(size_t)j * 64 + lane];
            float pa = p_lds[tq0][j];       // wave-uniform LDS broadcast
            float pb = p_lds[tq1][j];
            o0.x = fmaf(pa, vv.x, o0.x); o0.y = fmaf(pa, vv.y, o0.y);
            o0.z = fmaf(pa, vv.z, o0.z); o0.w = fmaf(pa, vv.w, o0.w);
            o1.x = fmaf(pb, vv.x, o1.x); o1.y = fmaf(pb, vv.y, o1.y);
            o1.z = fmaf(pb, vv.z, o1.z); o1.w = fmaf(pb, vv.w, o1.w);
        }

        float* Rrow0 = Rout + ((size_t)b * TT + t0 + tq0) * (2 * DD);
        float* Rrow1 = Rrow0 + 2 * DD;
        ((float4*)Rrow0)[lane] = o0;
        ((float4*)Rrow1)[lane] = o1;
        ((float4*)(Rrow0 + DD))[lane] = ((const float4*)qb)[lane];        // Q row 2w
        ((float4*)(Rrow1 + DD))[lane] = ((const float4*)(qb + DD))[lane]; // Q row 2w+1
    }
    __syncthreads();   // p_lds complete from all waves

    // ===== full alignment strip: 1024 rows x 32 floats (128B full lines) =====
    // 8 threads per row (8 x float4), 128 rows per pass, 8 passes.
    {
        const int rgrp = tid >> 3;          // 0..127
        const int cg   = tid & 7;
        float* abase = aligns + (size_t)b * NN * TT + t0 + cg * 4;
        #pragma unroll 4
        for (int pass = 0; pass < 8; ++pass) {
            int row = pass * 128 + rgrp;
            int iw  = row - prev;
            float4 v = make_float4(0.f, 0.f, 0.f, 0.f);
            if ((unsigned)iw < WIN) {
                v.x = p_lds[cg * 4 + 0][iw];
                v.y = p_lds[cg * 4 + 1][iw];
                v.z = p_lds[cg * 4 + 2][iw];
                v.w = p_lds[cg * 4 + 3][iw];
            }
            *(float4*)(abase + (size_t)row * TT) = v;
        }
    }
}

extern "C" void kernel_launch(void* const* d_in, const int* in_sizes, int n_in,
                              void* d_out, int out_size, void* d_ws, size_t ws_size,
                              hipStream_t stream) {
    const float* Q = (const float*)d_in[0];
    const float* K = (const float*)d_in[1];
    const float* V = (const float*)d_in[2];
    const int* prev = (const int*)d_in[3];
    float* out = (float*)d_out;

    // 32 blocks per batch x 16 batches = 512 blocks x 1024 threads.
    attn_v6<<<BB * TT / TBLK, NT, 0, stream>>>(Q, K, V, prev, out);
}

// Round 7
// 166.506 us; speedup vs baseline: 1.1861x; 1.1425x over previous
//
#include <hip/hip_runtime.h>

// B=16, T=1024, N=1024, D=256, WIN=64
// outputs (flat): R (B,T,2D) = [A@V, Q]   : 8388608 f32
//                 alignments (B,N,T) = A^T: 16777216 f32
//                 max_att (B,T)           : 16384 f32
//
// v7: decouple the two bottlenecks.
//  - zero_nonwin: streams zeros over the 960 NON-window alignment rows per
//    batch (63 MB) — no barriers, no LDS, 4KB contiguous per block-store.
//    (R5 measured this pattern at ~4.2 TB/s.)
//  - attn_v7: 1024 blocks x 256 thr (4 q/wave, 16 q/block). K window staged
//    in 128-d halves into padded LDS (38 KB total -> 4 blocks/CU). V direct
//    from global (L2-hot window). Writes R, maxatt, and ONLY the 64 window
//    alignment rows (64B full lines, t0 mult of 16) — disjoint from kernel 1.

#define BB 16
#define TT 1024
#define NN 1024
#define DD 256
#define WIN 64
#define TBLK 16          // queries per block
#define NT 256           // 4 waves, 4 queries each

#define R_ELEMS   (16u*1024u*512u)        // 8388608
#define ALN_ELEMS (16u*1024u*1024u)       // 16777216

#define LSTR 132         // LDS row stride (dwords); 132%32==4 -> conflict-free b128

__global__ __launch_bounds__(256) void zero_nonwin(
    float* __restrict__ aligns, const int* __restrict__ prev_in)
{
    const int b     = blockIdx.x >> 6;     // 64 blocks per batch
    const int chunk = blockIdx.x & 63;     // 15 non-window rows each
    const int prev  = prev_in[b];
    float4* base = (float4*)(aligns + (size_t)b * NN * TT);
    const float4 z = make_float4(0.f, 0.f, 0.f, 0.f);
    #pragma unroll
    for (int r = 0; r < 15; ++r) {
        int idx = chunk * 15 + r;          // 0..959 among non-window rows
        int n   = idx < prev ? idx : idx + WIN;
        base[(size_t)n * 256 + threadIdx.x] = z;   // 4KB contiguous
    }
}

__global__ __launch_bounds__(NT, 4) void attn_v7(
    const float* __restrict__ Q, const float* __restrict__ K,
    const float* __restrict__ V, const int* __restrict__ prev_in,
    float* __restrict__ out)
{
    __shared__ float ks[WIN * LSTR];        // 33792 B: K half-tile
    __shared__ float p_lds[TBLK][WIN + 4];  // 4352 B : probabilities [t][j]

    float* Rout   = out;
    float* aligns = out + R_ELEMS;
    float* maxatt = out + R_ELEMS + ALN_ELEMS;

    const int tid  = threadIdx.x;
    const int lane = tid & 63;
    const int w    = __builtin_amdgcn_readfirstlane(tid >> 6);  // wave 0..3 (uniform)
    const int b    = blockIdx.x >> 6;       // 64 blocks per batch
    const int t0   = (blockIdx.x & 63) * TBLK;
    const int prev = prev_in[b];

    const float* qb = Q + ((size_t)b * TT + t0 + 4 * w) * DD;   // scalar base

    // ================= QK^T over two 128-d halves =================
    float acc[4] = {0.f, 0.f, 0.f, 0.f};
    #pragma unroll
    for (int h = 0; h < 2; ++h) {
        if (h) __syncthreads();             // h0 readers done before restage
        const float4* Ksrc = (const float4*)(K + ((size_t)b * NN + prev) * DD + h * 128);
        #pragma unroll
        for (int k = 0; k < 8; ++k) {
            int t4 = tid + k * NT;          // 0..2047 float4 chunks
            int r = t4 >> 5, c = t4 & 31;
            float4 v = Ksrc[(size_t)r * 64 + c];
            *(float4*)&ks[r * LSTR + c * 4] = v;
        }
        __syncthreads();

        const float* qh = qb + h * 128;
        #pragma unroll 8
        for (int d4 = 0; d4 < 32; ++d4) {
            float4 kk = *(const float4*)&ks[lane * LSTR + d4 * 4];  // conflict-free b128
            #pragma unroll
            for (int t = 0; t < 4; ++t) {
                float4 q = ((const float4*)(qh + t * DD))[d4];      // wave-uniform
                acc[t] = fmaf(q.x, kk.x, fmaf(q.y, kk.y, fmaf(q.z, kk.z, fmaf(q.w, kk.w, acc[t]))));
            }
        }
    }

    // ================= softmax + argmax (wave-local), p -> LDS ===========
    #pragma unroll
    for (int t = 0; t < 4; ++t) {
        float v = acc[t] * 0.0625f;         // 1/sqrt(256)

        float m = v;
        #pragma unroll
        for (int off = 32; off; off >>= 1) m = fmaxf(m, __shfl_xor(m, off));

        float e = expf(v - m);
        float s = e;
        #pragma unroll
        for (int off = 32; off; off >>= 1) s += __shfl_xor(s, off);

        p_lds[4 * w + t][lane] = e / s;

        float av = v; int ai = lane;
        #pragma unroll
        for (int off = 32; off; off >>= 1) {
            float ov = __shfl_xor(av, off);
            int   oi = __shfl_xor(ai, off);
            if (ov > av || (ov == av && oi < ai)) { av = ov; ai = oi; }
        }
        if (lane == 0) maxatt[(size_t)b * TT + t0 + 4 * w + t] = (float)(prev + ai);
    }
    __syncthreads();                        // all 16 p rows visible

    // ===== window-row alignment strip: 64 rows x 16 floats (64B lines) ====
    // Kernel zero_nonwin never touches these rows -> written exactly once.
    {
        const int j = tid >> 2, cg = tid & 3;
        float4 v;
        v.x = p_lds[cg * 4 + 0][j];
        v.y = p_lds[cg * 4 + 1][j];
        v.z = p_lds[cg * 4 + 2][j];
        v.w = p_lds[cg * 4 + 3][j];
        *(float4*)(aligns + ((size_t)b * NN + prev + j) * TT + t0 + cg * 4) = v;
    }

    // ================= PV direct from global (L2-hot V) ==================
    // lane = d-chunk (64 x float4 = 256 d); reads own wave's p rows.
    {
        const float4* V4 = (const float4*)(V + ((size_t)b * NN + prev) * DD);
        float4 o[4];
        #pragma unroll
        for (int t = 0; t < 4; ++t) o[t] = make_float4(0.f, 0.f, 0.f, 0.f);

        #pragma unroll 4
        for (int j4 = 0; j4 < WIN / 4; ++j4) {
            float4 p0 = *(const float4*)&p_lds[4 * w + 0][j4 * 4];  // uniform bcast
            float4 p1 = *(const float4*)&p_lds[4 * w + 1][j4 * 4];
            float4 p2 = *(const float4*)&p_lds[4 * w + 2][j4 * 4];
            float4 p3 = *(const float4*)&p_lds[4 * w + 3][j4 * 4];
            float4 v0 = V4[(size_t)(j4 * 4 + 0) * 64 + lane];
            float4 v1 = V4[(size_t)(j4 * 4 + 1) * 64 + lane];
            float4 v2 = V4[(size_t)(j4 * 4 + 2) * 64 + lane];
            float4 v3 = V4[(size_t)(j4 * 4 + 3) * 64 + lane];
            #define ACC4(o_, p_) \
                o_.x = fmaf(p_.x, v0.x, fmaf(p_.y, v1.x, fmaf(p_.z, v2.x, fmaf(p_.w, v3.x, o_.x)))); \
                o_.y = fmaf(p_.x, v0.y, fmaf(p_.y, v1.y, fmaf(p_.z, v2.y, fmaf(p_.w, v3.y, o_.y)))); \
                o_.z = fmaf(p_.x, v0.z, fmaf(p_.y, v1.z, fmaf(p_.z, v2.z, fmaf(p_.w, v3.z, o_.z)))); \
                o_.w = fmaf(p_.x, v0.w, fmaf(p_.y, v1.w, fmaf(p_.z, v2.w, fmaf(p_.w, v3.w, o_.w))));
            ACC4(o[0], p0) ACC4(o[1], p1) ACC4(o[2], p2) ACC4(o[3], p3)
            #undef ACC4
        }

        #pragma unroll
        for (int t = 0; t < 4; ++t) {
            float* Rrow = Rout + ((size_t)b * TT + t0 + 4 * w + t) * (2 * DD);
            ((float4*)Rrow)[lane] = o[t];                               // A@V
            ((float4*)(Rrow + DD))[lane] = ((const float4*)(qb + t * DD))[lane];  // Q copy
        }
    }
}

extern "C" void kernel_launch(void* const* d_in, const int* in_sizes, int n_in,
                              void* d_out, int out_size, void* d_ws, size_t ws_size,
                              hipStream_t stream) {
    const float* Q = (const float*)d_in[0];
    const float* K = (const float*)d_in[1];
    const float* V = (const float*)d_in[2];
    const int* prev = (const int*)d_in[3];
    float* out = (float*)d_out;

    // 1) stream zeros over the 960 non-window rows per batch (63 MB)
    zero_nonwin<<<1024, 256, 0, stream>>>(out + R_ELEMS, prev);
    // 2) attention: R, maxatt, and the 64 window alignment rows per batch
    attn_v7<<<BB * TT / TBLK, NT, 0, stream>>>(Q, K, V, prev, out);
}